// Round 7
// baseline (81.837 us; speedup 1.0000x reference)
//
#include <hip/hip_runtime.h>
#include <math.h>

#define REG_COEF 25.0f
#define B 8
#define H 3
#define N 4096

typedef _Float16 f16x8 __attribute__((ext_vector_type(8)));
typedef float f32x16 __attribute__((ext_vector_type(16)));

static constexpr int NX = B * N;          // 32768 sample points (A-role)
static constexpr int NY = B * H * N;      // 98304 reflected points (B-role)
static constexpr int NM = 2 * B * H * N;  // 196608 per-point mins

// ws layout (float units):
//   [0, 262144)        : Afrag — NX points x 16 f16 slots (32 B each)
//   [262144, 1048576)  : Bfrag — NY points x 16 f16 slots (32 B each)
//   [1048576, 1245184) : mins (196608 floats)

__global__ void prep_kernel(const float* __restrict__ pts, const float* __restrict__ ypred,
                            char* __restrict__ Af, char* __restrict__ Bf,
                            float* __restrict__ mins, float* __restrict__ out)
{
    int idx = blockIdx.x * blockDim.x + threadIdx.x;
    if (idx == 0) {
        float reg = 0.f;
        for (int b = 0; b < B; ++b) {
            float n[H][3];
            #pragma unroll
            for (int h = 0; h < H; ++h) {
                float a0 = ypred[b * 12 + h * 4 + 0];
                float a1 = ypred[b * 12 + h * 4 + 1];
                float a2 = ypred[b * 12 + h * 4 + 2];
                float inv = rsqrtf(a0 * a0 + a1 * a1 + a2 * a2);
                n[h][0] = a0 * inv; n[h][1] = a1 * inv; n[h][2] = a2 * inv;
            }
            float s = 0.f;
            #pragma unroll
            for (int c = 0; c < H; ++c)
                #pragma unroll
                for (int e = 0; e < H; ++e) {
                    float g = n[c][0] * n[e][0] + n[c][1] * n[e][1] + n[c][2] * n[e][2];
                    if (c == e) g -= 1.f;
                    s += g * g;
                }
            reg += sqrtf(s);
        }
        out[0] = REG_COEF * reg;   // reduce_kernel accumulates on top
    }

    union { _Float16 h[16]; uint4 u[2]; } pk;

    if (idx < NX) {
        // X point -> A slots: a = -2*coord, hi/lo split; w = |q|^2 hi/lo
        const float* p = pts + (size_t)idx * 3;
        float x = p[0], y = p[1], z = p[2];
        float w = x * x + y * y + z * z;
        float ax = -2.f * x, ay = -2.f * y, az = -2.f * z;
        _Float16 ahx = (_Float16)ax, ahy = (_Float16)ay, ahz = (_Float16)az;
        _Float16 wh = (_Float16)w;
        pk.h[0] = ahx; pk.h[1] = ahy; pk.h[2] = ahz;
        pk.h[3] = (_Float16)(ax - (float)ahx);
        pk.h[4] = (_Float16)(ay - (float)ahy);
        pk.h[5] = (_Float16)(az - (float)ahz);
        pk.h[6] = ahx; pk.h[7] = ahy; pk.h[8] = ahz;
        pk.h[9] = wh; pk.h[10] = (_Float16)(w - (float)wh);
        pk.h[11] = (_Float16)1.f; pk.h[12] = (_Float16)1.f;
        pk.h[13] = (_Float16)0.f; pk.h[14] = (_Float16)0.f; pk.h[15] = (_Float16)0.f;
        uint4* dst = (uint4*)(Af + (size_t)idx * 32);
        dst[0] = pk.u[0]; dst[1] = pk.u[1];
    } else if (idx < NX + NY) {
        int t = idx - NX;            // (b*H + h)*N + nn
        int nn = t & (N - 1);
        int bh = t >> 12;
        int b = bh / H, h = bh - b * H;
        float a0 = ypred[b * 12 + h * 4 + 0];
        float a1 = ypred[b * 12 + h * 4 + 1];
        float a2 = ypred[b * 12 + h * 4 + 2];
        float off = ypred[b * 12 + h * 4 + 3];
        float inv = rsqrtf(a0 * a0 + a1 * a1 + a2 * a2);
        a0 *= inv; a1 *= inv; a2 *= inv;
        const float* p = pts + ((size_t)b * N + nn) * 3;
        float x0 = p[0], x1 = p[1], x2 = p[2];
        float dist = a0 * x0 + a1 * x1 + a2 * x2 + off;
        float x = fmaf(-2.f * dist, a0, x0);
        float y = fmaf(-2.f * dist, a1, x1);
        float z = fmaf(-2.f * dist, a2, x2);
        float w = x * x + y * y + z * z;
        _Float16 thx = (_Float16)x, thy = (_Float16)y, thz = (_Float16)z;
        _Float16 wh = (_Float16)w;
        pk.h[0] = thx; pk.h[1] = thy; pk.h[2] = thz;
        pk.h[3] = thx; pk.h[4] = thy; pk.h[5] = thz;
        pk.h[6] = (_Float16)(x - (float)thx);
        pk.h[7] = (_Float16)(y - (float)thy);
        pk.h[8] = (_Float16)(z - (float)thz);
        pk.h[9] = (_Float16)1.f; pk.h[10] = (_Float16)1.f;
        pk.h[11] = wh; pk.h[12] = (_Float16)(w - (float)wh);
        pk.h[13] = (_Float16)0.f; pk.h[14] = (_Float16)0.f; pk.h[15] = (_Float16)0.f;
        uint4* dst = (uint4*)(Bf + (size_t)t * 32);
        dst[0] = pk.u[0]; dst[1] = pk.u[1];
    } else if (idx < NX + NY + NM) {
        mins[idx - NX - NY] = __uint_as_float(0x7F800000u);  // +inf
    }
}

// 768 blocks: [tsplit(4)][qsplit(8)][h(3)][b(8)]
// Block: 4 waves x 128 queries (4 A-frags in regs), streams 1024 targets
// (32 B-tiles). Each mfma_f32_32x32x16_f16 yields a 32x32 tile of FULL
// distances d(q,t) (f16 hi/lo split packing, ~1e-4 accurate). One pass
// serves both chamfer directions: per-row reg chains (q-side) + per-col
// lane tree -> LDS atomicMin (t-side).
__global__ __launch_bounds__(256, 2) void chamfer_kernel(const char* __restrict__ Af,
                                                         const char* __restrict__ Bf,
                                                         float* __restrict__ mins)
{
    __shared__ unsigned tmin[1024];
    int bid = blockIdx.x;
    int ts = bid & 3;
    int qs = (bid >> 2) & 7;
    int rest = bid >> 5;        // 0..23
    int hh = rest % 3;
    int b  = rest / 3;

    int tid = threadIdx.x;
    int w = tid >> 6;
    int lane = tid & 63;
    int l31 = lane & 31, kb = lane >> 5;

    for (int j = tid; j < 1024; j += 256) tmin[j] = 0x7F800000u;
    __syncthreads();

    int qbase = qs * 512 + w * 128;   // query offset within batch b
    f16x8 A[4];
    #pragma unroll
    for (int a = 0; a < 4; ++a)
        A[a] = *(const f16x8*)(Af + ((size_t)(b * N + qbase + a * 32 + l31)) * 32 + kb * 16);

    f32x16 mq[4];
    #pragma unroll
    for (int a = 0; a < 4; ++a)
        #pragma unroll
        for (int r = 0; r < 16; ++r) mq[a][r] = INFINITY;

    const char* Bbase = Bf + ((size_t)((b * H + hh) * N + ts * 1024 + l31)) * 32 + kb * 16;
    f16x8 Bcur = *(const f16x8*)(Bbase);
    f32x16 zero = {};

    for (int bt = 0; bt < 32; ++bt) {
        f16x8 Bnext = Bcur;
        if (bt < 31) Bnext = *(const f16x8*)(Bbase + (size_t)(bt + 1) * 1024);
        float tacc = INFINITY;
        #pragma unroll
        for (int a = 0; a < 4; ++a) {
            f32x16 D = __builtin_amdgcn_mfma_f32_32x32x16_f16(A[a], Bcur, zero, 0, 0, 0);
            #pragma unroll
            for (int r = 0; r < 16; ++r) mq[a][r] = fminf(mq[a][r], D[r]);
            float t0 = fminf(fminf(D[0], D[1]), fminf(D[2], D[3]));
            float t1 = fminf(fminf(D[4], D[5]), fminf(D[6], D[7]));
            float t2 = fminf(fminf(D[8], D[9]), fminf(D[10], D[11]));
            float t3 = fminf(fminf(D[12], D[13]), fminf(D[14], D[15]));
            tacc = fminf(tacc, fminf(fminf(t0, t1), fminf(t2, t3)));
        }
        float o = __shfl_xor(tacc, 32, 64);
        tacc = fmaxf(fminf(tacc, o), 0.f);
        if (lane < 32) atomicMin(&tmin[bt * 32 + lane], __float_as_uint(tacc));
        Bcur = Bnext;
    }

    // q-side: reduce each row-chain across the 32 columns (lanes)
    #pragma unroll
    for (int a = 0; a < 4; ++a) {
        #pragma unroll
        for (int r = 0; r < 16; ++r) {
            float v = mq[a][r];
            v = fminf(v, __shfl_xor(v, 1, 64));
            v = fminf(v, __shfl_xor(v, 2, 64));
            v = fminf(v, __shfl_xor(v, 4, 64));
            v = fminf(v, __shfl_xor(v, 8, 64));
            v = fminf(v, __shfl_xor(v, 16, 64));
            if (l31 == 0) {
                int row = (r & 3) + 8 * (r >> 2) + 4 * kb;
                atomicMin((unsigned*)&mins[(size_t)(b * H + hh) * N + qbase + a * 32 + row],
                          __float_as_uint(fmaxf(v, 0.f)));
            }
        }
    }

    __syncthreads();
    float* minsT = mins + (size_t)B * H * N + (size_t)(b * H + hh) * N + ts * 1024;
    for (int j = tid; j < 1024; j += 256)
        atomicMin((unsigned*)&minsT[j], tmin[j]);
}

__global__ void reduce_kernel(const float* __restrict__ mins, float* __restrict__ out)
{
    int tid = blockIdx.x * blockDim.x + threadIdx.x;  // 192*256 = 49152 threads
    float s = 0.f;
    #pragma unroll
    for (int k = 0; k < 4; ++k) s += mins[tid + k * 49152];
    #pragma unroll
    for (int off = 32; off > 0; off >>= 1) s += __shfl_down(s, off);
    if ((threadIdx.x & 63) == 0) atomicAdd(out, s);
}

extern "C" void kernel_launch(void* const* d_in, const int* in_sizes, int n_in,
                              void* d_out, int out_size, void* d_ws, size_t ws_size,
                              hipStream_t stream)
{
    const float* pts = (const float*)d_in[0];   // (8,4096,3) fp32
    const float* yp  = (const float*)d_in[1];   // (8,3,4) fp32
    float* out = (float*)d_out;
    float* ws  = (float*)d_ws;

    char* Af   = (char*)ws;                     // 1 MB
    char* Bf   = (char*)(ws + 262144);          // 3 MB
    float* mins = ws + 1048576;                 // 196608 floats

    prep_kernel<<<1280, 256, 0, stream>>>(pts, yp, Af, Bf, mins, out);
    chamfer_kernel<<<768, 256, 0, stream>>>(Af, Bf, mins);
    reduce_kernel<<<192, 256, 0, stream>>>(mins, out);
}